// Round 3
// baseline (846.421 us; speedup 1.0000x reference)
//
#include <hip/hip_runtime.h>

// B=2,H=16,S=2048,D=64 fp32; temp=8; outputs: O [B,H,S,D] then attn [B,H,S,S].
// v4: K/V pre-converted to bf16 in workspace (fallback PRE=0 reads fp32 direct);
// K MFMA fragments loaded straight from global (no K LDS, pass 1 barrier-free);
// pass 2 V-only LDS double-buffered (1 barrier/tile), v3's verified tr-read
// granules; exp2 with log2e/8 folded into Q prescale; nt attn stores.

#define S 2048
#define D 64
#define HH 16
#define BB 2
#define NE (BB * HH * S * D)  // elems per K or V array

typedef __attribute__((ext_vector_type(8))) short short8;
typedef __attribute__((ext_vector_type(4))) float f32x4;
typedef __attribute__((ext_vector_type(2))) unsigned int u32x2;

__device__ __forceinline__ unsigned int packbf2(float a, float b) {
  union { __bf16 h[2]; unsigned int u; } r;
  r.h[0] = (__bf16)a;  // RNE fptrunc -> v_cvt_pk_bf16_f32 on gfx950
  r.h[1] = (__bf16)b;
  return r.u;
}
__device__ __forceinline__ short8 cvt8(float4 a, float4 b) {
  union { unsigned int u[4]; short8 s; } r;
  r.u[0] = packbf2(a.x, a.y); r.u[1] = packbf2(a.z, a.w);
  r.u[2] = packbf2(b.x, b.y); r.u[3] = packbf2(b.z, b.w);
  return r.s;
}
#define QSC 0.1803368801111204f  // (1/8) * log2(e): scores arrive in log2 domain
__device__ __forceinline__ float4 qscale(float4 v) {
  return make_float4(v.x * QSC, v.y * QSC, v.z * QSC, v.w * QSC);
}
__device__ __forceinline__ float exp2fast(float x) {
  float r;
  asm("v_exp_f32 %0, %1" : "=v"(r) : "v"(x));  // D = 2^S0
  return r;
}

// hardware transpose read: granule = (addr & ~127); column = (addr & 127)/8;
// returns rows 0..3 (bytes granule + col*2 + {0,32,64,96})
#define TRRD(dst, addr, off) \
  asm volatile("ds_read_b64_tr_b16 %0, %1 offset:" #off : "=v"(dst) : "v"(addr))

// ---- pre-pass: pack mask ints -> 1 bit per element (u64 covers 64 keys) ----
__global__ __launch_bounds__(256) void pack_mask_kernel(
    const int* __restrict__ m, unsigned long long* __restrict__ bits) {
  int wid = blockIdx.x * 4 + (threadIdx.x >> 6);
  int lane = threadIdx.x & 63;
  int v = m[(size_t)wid * 64 + lane];
  unsigned long long b = __ballot(v != 0);
  if (lane == 0) bits[wid] = b;
}

// ---- pre-pass: K/V fp32 -> bf16 (halves L2/L3 re-read traffic) ----
__global__ __launch_bounds__(256) void cvt_kv_kernel(
    const float* __restrict__ K, const float* __restrict__ V,
    unsigned short* __restrict__ Kb, unsigned short* __restrict__ Vb) {
  size_t i = ((size_t)blockIdx.x * 256 + threadIdx.x) * 8;
  const float* s;
  unsigned short* d;
  if (i < (size_t)NE) { s = K + i; d = Kb + i; }
  else { s = V + (i - NE); d = Vb + (i - NE); }
  float4 a = *reinterpret_cast<const float4*>(s);
  float4 b = *reinterpret_cast<const float4*>(s + 4);
  *reinterpret_cast<short8*>(d) = cvt8(a, b);
}

template <int PRE>
__global__ __launch_bounds__(256) void attn_kernel(
    const float* __restrict__ Qg, const void* __restrict__ Kx,
    const void* __restrict__ Vx, const unsigned long long* __restrict__ Mb,
    float* __restrict__ Og, float* __restrict__ Ag) {
  __shared__ alignas(128) unsigned short Vt[2][4096];  // dbuf; 64 granules of 4x16

  const int tid = threadIdx.x;
  const int w = tid >> 6;
  const int lane = tid & 63;
  const int ln15 = lane & 15;
  const int quad = lane >> 4;

  const int bh = blockIdx.x;  // bh fastest -> each XCD sees ~4 heads
  const int qtile = blockIdx.y;
  const int b = bh >> 4;
  const size_t qkvbase = (size_t)bh * S * D;
  const int q0 = qtile * 64;
  const int qrow = q0 + w * 16 + ln15;

  // Q fragments, pre-scaled by log2e/temp (scores emerge in log2 domain)
  const float4* qp = reinterpret_cast<const float4*>(Qg + qkvbase + (size_t)qrow * D);
  short8 aq0, aq1;
  {
    float4 a0 = qscale(qp[quad * 2]), a1 = qscale(qp[quad * 2 + 1]);
    float4 b0 = qscale(qp[8 + quad * 2]), b1 = qscale(qp[8 + quad * 2 + 1]);
    aq0 = cvt8(a0, a1);
    aq1 = cvt8(b0, b1);
  }

  const unsigned long long* mrow = Mb + ((size_t)b * S + qrow) * (S / 64);

  // K fragment base for this lane: row = t*64 + kt*16 + ln15, col = quad*8
  const unsigned short* pkh =
      reinterpret_cast<const unsigned short*>(Kx) + qkvbase + (size_t)ln15 * D + quad * 8;
  const float* pkf =
      reinterpret_cast<const float*>(Kx) + qkvbase + (size_t)ln15 * D + quad * 8;

  auto loadK = [&](int row, short8& b0, short8& b1) {
    if constexpr (PRE) {
      const unsigned short* p = pkh + (size_t)row * D;
      b0 = *reinterpret_cast<const short8*>(p);
      b1 = *reinterpret_cast<const short8*>(p + 32);
    } else {
      const float* p = pkf + (size_t)row * D;
      float4 a0 = *reinterpret_cast<const float4*>(p);
      float4 a1 = *reinterpret_cast<const float4*>(p + 4);
      float4 c0 = *reinterpret_cast<const float4*>(p + 32);
      float4 c1 = *reinterpret_cast<const float4*>(p + 36);
      b0 = cvt8(a0, a1);
      b1 = cvt8(c0, c1);
    }
  };

  // =============== PASS 1: barrier-free lsum streaming ===============
  float lsum = 0.f;
#pragma unroll 2
  for (int t = 0; t < 32; ++t) {
    unsigned long long mw = mrow[t];
#pragma unroll
    for (int kt = 0; kt < 4; ++kt) {
      short8 bk0, bk1;
      loadK(t * 64 + kt * 16, bk0, bk1);
      f32x4 acc = {0.f, 0.f, 0.f, 0.f};
      acc = __builtin_amdgcn_mfma_f32_16x16x32_bf16(bk0, aq0, acc, 0, 0, 0);
      acc = __builtin_amdgcn_mfma_f32_16x16x32_bf16(bk1, aq1, acc, 0, 0, 0);
      unsigned int nib = (unsigned int)(mw >> (kt * 16 + quad * 4)) & 0xFu;
#pragma unroll
      for (int r = 0; r < 4; ++r) {
        float e = exp2fast(acc[r]);
        lsum += ((nib >> r) & 1u) ? e : 0.f;
      }
    }
  }
  lsum += __shfl_xor(lsum, 16, 64);
  lsum += __shfl_xor(lsum, 32, 64);
  const float rinv = (lsum > 0.f) ? 1.f / lsum : 0.f;

  // =============== PASS 2: attn store + O = P*V (V dbuf, 1 barrier/tile) ====
  float* arow = Ag + ((size_t)bh * S + qrow) * S;
  f32x4 oacc[4] = {{0.f, 0.f, 0.f, 0.f}, {0.f, 0.f, 0.f, 0.f},
                   {0.f, 0.f, 0.f, 0.f}, {0.f, 0.f, 0.f, 0.f}};

  // V granule layout (verified v3): G = (key>>2)*4 + (d>>4), elem (key&3)*16+(d&15)
  const int trow = tid >> 2;          // staged key row
  const int d0c = (tid & 3) << 4;     // staged d offset (16 elems)
  const int vwoff = ((trow >> 2) * 4 + (tid & 3)) * 64 + (trow & 3) * 16;
  const unsigned int vb0 =
      (unsigned int)(unsigned long long)(const void*)&Vt[0][0] +
      (unsigned int)(quad * 512 + ln15 * 8);

  const unsigned short* pvh =
      reinterpret_cast<const unsigned short*>(Vx) + qkvbase + (size_t)trow * D + d0c;
  const float* pvf =
      reinterpret_cast<const float*>(Vx) + qkvbase + (size_t)trow * D + d0c;

  short8 hv0, hv1;
  float4 fv0, fv1, fv2, fv3;
  auto loadV = [&](int t) {
    if constexpr (PRE) {
      const unsigned short* p = pvh + (size_t)t * 64 * D;
      hv0 = *reinterpret_cast<const short8*>(p);
      hv1 = *reinterpret_cast<const short8*>(p + 8);
    } else {
      const float* p = pvf + (size_t)t * 64 * D;
      fv0 = reinterpret_cast<const float4*>(p)[0];
      fv1 = reinterpret_cast<const float4*>(p)[1];
      fv2 = reinterpret_cast<const float4*>(p)[2];
      fv3 = reinterpret_cast<const float4*>(p)[3];
    }
  };
  auto writeV = [&](int buf) {
    unsigned short* dst = &Vt[buf][vwoff];
    if constexpr (PRE) {
      *reinterpret_cast<short8*>(dst) = hv0;
      *reinterpret_cast<short8*>(dst + 8) = hv1;
    } else {
      *reinterpret_cast<short8*>(dst) = cvt8(fv0, fv1);
      *reinterpret_cast<short8*>(dst + 8) = cvt8(fv2, fv3);
    }
  };

  loadV(0);
  writeV(0);
  loadV(1);
  __syncthreads();

  for (int t = 0; t < 32; ++t) {
    const int cur = t & 1;
    if (t < 31) writeV(cur ^ 1);  // vf regs hold tile t+1
    if (t < 30) loadV(t + 2);
    unsigned long long mw = mrow[t];
    const int k0 = t * 64;
    unsigned int apu[8];
#pragma unroll
    for (int kt = 0; kt < 4; ++kt) {
      short8 bk0, bk1;
      loadK(t * 64 + kt * 16, bk0, bk1);
      f32x4 acc = {0.f, 0.f, 0.f, 0.f};
      acc = __builtin_amdgcn_mfma_f32_16x16x32_bf16(bk0, aq0, acc, 0, 0, 0);
      acc = __builtin_amdgcn_mfma_f32_16x16x32_bf16(bk1, aq1, acc, 0, 0, 0);
      unsigned int nib = (unsigned int)(mw >> (kt * 16 + quad * 4)) & 0xFu;
      f32x4 p;
#pragma unroll
      for (int r = 0; r < 4; ++r) {
        float e = exp2fast(acc[r]) * rinv;
        p[r] = ((nib >> r) & 1u) ? e : 0.f;
      }
      __builtin_nontemporal_store(p, reinterpret_cast<f32x4*>(arow + k0 + kt * 16 + quad * 4));
      // lane owns P[query ln15][key kt*16 + quad*4 + r]; identical key permute on B
      apu[kt * 2] = packbf2(p[0], p[1]);
      apu[kt * 2 + 1] = packbf2(p[2], p[3]);
    }
    // B-frags via tr-reads (v3-verified); granule (m*8+h*4+quad)*4+c, col ln15
    const unsigned int vb = vb0 + (unsigned int)(cur << 13);
    u32x2 x0, x1, x2, x3, x4, x5, x6, x7, x8, x9, x10, x11, x12, x13, x14, x15;
    TRRD(x0, vb, 0);     TRRD(x1, vb, 2048);
    TRRD(x2, vb, 128);   TRRD(x3, vb, 2176);
    TRRD(x4, vb, 256);   TRRD(x5, vb, 2304);
    TRRD(x6, vb, 384);   TRRD(x7, vb, 2432);
    TRRD(x8, vb, 4096);  TRRD(x9, vb, 6144);
    TRRD(x10, vb, 4224); TRRD(x11, vb, 6272);
    TRRD(x12, vb, 4352); TRRD(x13, vb, 6400);
    TRRD(x14, vb, 4480); TRRD(x15, vb, 6528);
    asm volatile("s_waitcnt lgkmcnt(0)" ::: "memory");
    __builtin_amdgcn_sched_barrier(0);  // rule-18: keep MFMAs below the wait
    union Frag { unsigned int u[4]; u32x2 d[2]; short8 s; };
    Frag ap0, ap1, bv;
    ap0.u[0] = apu[0]; ap0.u[1] = apu[1]; ap0.u[2] = apu[2]; ap0.u[3] = apu[3];
    ap1.u[0] = apu[4]; ap1.u[1] = apu[5]; ap1.u[2] = apu[6]; ap1.u[3] = apu[7];
    bv.d[0] = x0;  bv.d[1] = x1;
    oacc[0] = __builtin_amdgcn_mfma_f32_16x16x32_bf16(ap0.s, bv.s, oacc[0], 0, 0, 0);
    bv.d[0] = x2;  bv.d[1] = x3;
    oacc[1] = __builtin_amdgcn_mfma_f32_16x16x32_bf16(ap0.s, bv.s, oacc[1], 0, 0, 0);
    bv.d[0] = x4;  bv.d[1] = x5;
    oacc[2] = __builtin_amdgcn_mfma_f32_16x16x32_bf16(ap0.s, bv.s, oacc[2], 0, 0, 0);
    bv.d[0] = x6;  bv.d[1] = x7;
    oacc[3] = __builtin_amdgcn_mfma_f32_16x16x32_bf16(ap0.s, bv.s, oacc[3], 0, 0, 0);
    bv.d[0] = x8;  bv.d[1] = x9;
    oacc[0] = __builtin_amdgcn_mfma_f32_16x16x32_bf16(ap1.s, bv.s, oacc[0], 0, 0, 0);
    bv.d[0] = x10; bv.d[1] = x11;
    oacc[1] = __builtin_amdgcn_mfma_f32_16x16x32_bf16(ap1.s, bv.s, oacc[1], 0, 0, 0);
    bv.d[0] = x12; bv.d[1] = x13;
    oacc[2] = __builtin_amdgcn_mfma_f32_16x16x32_bf16(ap1.s, bv.s, oacc[2], 0, 0, 0);
    bv.d[0] = x14; bv.d[1] = x15;
    oacc[3] = __builtin_amdgcn_mfma_f32_16x16x32_bf16(ap1.s, bv.s, oacc[3], 0, 0, 0);
    __syncthreads();
  }

  // epilogue: O store (C rows = query offset quad*4+r, cols = d = c*16+ln15)
#pragma unroll
  for (int c = 0; c < 4; ++c) {
#pragma unroll
    for (int r = 0; r < 4; ++r) {
      Og[qkvbase + (size_t)(q0 + w * 16 + quad * 4 + r) * D + c * 16 + ln15] = oacc[c][r];
    }
  }
}

extern "C" void kernel_launch(void* const* d_in, const int* in_sizes, int n_in,
                              void* d_out, int out_size, void* d_ws, size_t ws_size,
                              hipStream_t stream) {
  const float* q = (const float*)d_in[0];
  const float* k = (const float*)d_in[1];
  const float* v = (const float*)d_in[2];
  const int* m = (const int*)d_in[3];
  float* outp = (float*)d_out;
  float* attnp = outp + (size_t)BB * HH * S * D;

  const size_t bitsBytes = (size_t)BB * S * (S / 64) * 8;  // 1 MB
  unsigned long long* bits = (unsigned long long*)d_ws;
  unsigned short* Kb = (unsigned short*)((char*)d_ws + bitsBytes);
  unsigned short* Vb = Kb + (size_t)NE;
  const bool pre = ws_size >= bitsBytes + 2 * (size_t)NE * sizeof(unsigned short);

  const int nwords = BB * S * (S / 64);  // 131072
  pack_mask_kernel<<<nwords / 4, 256, 0, stream>>>(m, bits);
  dim3 grid(BB * HH, S / 64);
  if (pre) {
    cvt_kv_kernel<<<(2 * (size_t)NE / 8) / 256, 256, 0, stream>>>(k, v, Kb, Vb);
    attn_kernel<1><<<grid, 256, 0, stream>>>(q, Kb, Vb, bits, outp, attnp);
  } else {
    attn_kernel<0><<<grid, 256, 0, stream>>>(q, k, v, bits, outp, attnp);
  }
}

// Round 4
// 838.800 us; speedup vs baseline: 1.0091x; 1.0091x over previous
//
#include <hip/hip_runtime.h>

// B=2,H=16,S=2048,D=64 fp32; temp=8; outputs: O [B,H,S,D] then attn [B,H,S,S].
// v5: plain (non-nt) attn stores so vmcnt drains at L2 speed; V staged via
// global_load_lds with pre-swizzled bf16 source (no ds_write conflicts, no reg
// round-trip); batched K loads; setprio around PV MFMA cluster. Keeps v3's
// verified tr-read granule layout and the barrier-free pass 1.

#define S 2048
#define D 64
#define HH 16
#define BB 2
#define NE (BB * HH * S * D)  // elems per K or V array

typedef __attribute__((ext_vector_type(8))) short short8;
typedef __attribute__((ext_vector_type(4))) float f32x4;
typedef __attribute__((ext_vector_type(2))) unsigned int u32x2;

__device__ __forceinline__ unsigned int packbf2(float a, float b) {
  union { __bf16 h[2]; unsigned int u; } r;
  r.h[0] = (__bf16)a;  // RNE fptrunc -> v_cvt_pk_bf16_f32 on gfx950
  r.h[1] = (__bf16)b;
  return r.u;
}
__device__ __forceinline__ short8 cvt8(float4 a, float4 b) {
  union { unsigned int u[4]; short8 s; } r;
  r.u[0] = packbf2(a.x, a.y); r.u[1] = packbf2(a.z, a.w);
  r.u[2] = packbf2(b.x, b.y); r.u[3] = packbf2(b.z, b.w);
  return r.s;
}
#define QSC 0.1803368801111204f  // (1/8) * log2(e): scores arrive in log2 domain
__device__ __forceinline__ float4 qscale(float4 v) {
  return make_float4(v.x * QSC, v.y * QSC, v.z * QSC, v.w * QSC);
}
__device__ __forceinline__ float exp2fast(float x) {
  float r;
  asm("v_exp_f32 %0, %1" : "=v"(r) : "v"(x));  // D = 2^S0
  return r;
}
__device__ __forceinline__ void gload_lds16(const void* g, void* l) {
  __builtin_amdgcn_global_load_lds(
      (const __attribute__((address_space(1))) void*)g,
      (__attribute__((address_space(3))) void*)l, 16, 0, 0);
}

// hardware transpose read: granule = (addr & ~127); column = (addr & 127)/8;
// returns rows 0..3 (bytes granule + col*2 + {0,32,64,96})
#define TRRD(dst, addr, off) \
  asm volatile("ds_read_b64_tr_b16 %0, %1 offset:" #off : "=v"(dst) : "v"(addr))

// ---- pre-pass: pack mask ints -> 1 bit per element (u64 covers 64 keys) ----
__global__ __launch_bounds__(256) void pack_mask_kernel(
    const int* __restrict__ m, unsigned long long* __restrict__ bits) {
  int wid = blockIdx.x * 4 + (threadIdx.x >> 6);
  int lane = threadIdx.x & 63;
  int v = m[(size_t)wid * 64 + lane];
  unsigned long long b = __ballot(v != 0);
  if (lane == 0) bits[wid] = b;
}

// ---- pre-pass: K/V fp32 -> bf16 (halves L2/L3 re-read traffic) ----
__global__ __launch_bounds__(256) void cvt_kv_kernel(
    const float* __restrict__ K, const float* __restrict__ V,
    unsigned short* __restrict__ Kb, unsigned short* __restrict__ Vb) {
  size_t i = ((size_t)blockIdx.x * 256 + threadIdx.x) * 8;
  const float* s;
  unsigned short* d;
  if (i < (size_t)NE) { s = K + i; d = Kb + i; }
  else { s = V + (i - NE); d = Vb + (i - NE); }
  float4 a = *reinterpret_cast<const float4*>(s);
  float4 b = *reinterpret_cast<const float4*>(s + 4);
  *reinterpret_cast<short8*>(d) = cvt8(a, b);
}

template <int PRE>
__global__ __launch_bounds__(256) void attn_kernel(
    const float* __restrict__ Qg, const void* __restrict__ Kx,
    const void* __restrict__ Vx, const unsigned long long* __restrict__ Mb,
    float* __restrict__ Og, float* __restrict__ Ag) {
  __shared__ alignas(128) unsigned short Vt[2][4096];  // dbuf; 64 granules of 4x16

  const int tid = threadIdx.x;
  const int w = tid >> 6;
  const int lane = tid & 63;
  const int ln15 = lane & 15;
  const int quad = lane >> 4;

  const int bh = blockIdx.x;  // bh fastest -> each XCD sees ~4 heads
  const int qtile = blockIdx.y;
  const int b = bh >> 4;
  const size_t qkvbase = (size_t)bh * S * D;
  const int q0 = qtile * 64;
  const int qrow = q0 + w * 16 + ln15;

  // Q fragments, pre-scaled by log2e/temp (scores emerge in log2 domain)
  const float4* qp = reinterpret_cast<const float4*>(Qg + qkvbase + (size_t)qrow * D);
  short8 aq0, aq1;
  {
    float4 a0 = qscale(qp[quad * 2]), a1 = qscale(qp[quad * 2 + 1]);
    float4 b0 = qscale(qp[8 + quad * 2]), b1 = qscale(qp[8 + quad * 2 + 1]);
    aq0 = cvt8(a0, a1);
    aq1 = cvt8(b0, b1);
  }

  const unsigned long long* mrow = Mb + ((size_t)b * S + qrow) * (S / 64);

  // K fragment base for this lane: row = t*64 + kt*16 + ln15, col = quad*8
  const unsigned short* pkh =
      reinterpret_cast<const unsigned short*>(Kx) + qkvbase + (size_t)ln15 * D + quad * 8;
  const float* pkf =
      reinterpret_cast<const float*>(Kx) + qkvbase + (size_t)ln15 * D + quad * 8;

  auto loadK = [&](int row, short8& b0, short8& b1) {
    if constexpr (PRE) {
      const unsigned short* p = pkh + (size_t)row * D;
      b0 = *reinterpret_cast<const short8*>(p);
      b1 = *reinterpret_cast<const short8*>(p + 32);
    } else {
      const float* p = pkf + (size_t)row * D;
      float4 a0 = *reinterpret_cast<const float4*>(p);
      float4 a1 = *reinterpret_cast<const float4*>(p + 4);
      float4 c0 = *reinterpret_cast<const float4*>(p + 32);
      float4 c1 = *reinterpret_cast<const float4*>(p + 36);
      b0 = cvt8(a0, a1);
      b1 = cvt8(c0, c1);
    }
  };

  // =============== PASS 1: barrier-free lsum streaming ===============
  float lsum = 0.f;
#pragma unroll 2
  for (int t = 0; t < 32; ++t) {
    unsigned long long mw = mrow[t];
    short8 bk[4][2];
#pragma unroll
    for (int kt = 0; kt < 4; ++kt) loadK(t * 64 + kt * 16, bk[kt][0], bk[kt][1]);
#pragma unroll
    for (int kt = 0; kt < 4; ++kt) {
      f32x4 acc = {0.f, 0.f, 0.f, 0.f};
      acc = __builtin_amdgcn_mfma_f32_16x16x32_bf16(bk[kt][0], aq0, acc, 0, 0, 0);
      acc = __builtin_amdgcn_mfma_f32_16x16x32_bf16(bk[kt][1], aq1, acc, 0, 0, 0);
      unsigned int nib = (unsigned int)(mw >> (kt * 16 + quad * 4)) & 0xFu;
#pragma unroll
      for (int r = 0; r < 4; ++r) {
        float e = exp2fast(acc[r]);
        lsum += ((nib >> r) & 1u) ? e : 0.f;
      }
    }
  }
  lsum += __shfl_xor(lsum, 16, 64);
  lsum += __shfl_xor(lsum, 32, 64);
  const float rinv = (lsum > 0.f) ? 1.f / lsum : 0.f;

  // =============== PASS 2: attn store + O = P*V (V dbuf, 1 barrier/tile) ====
  float* arow = Ag + ((size_t)bh * S + qrow) * S;
  f32x4 oacc[4] = {{0.f, 0.f, 0.f, 0.f}, {0.f, 0.f, 0.f, 0.f},
                   {0.f, 0.f, 0.f, 0.f}, {0.f, 0.f, 0.f, 0.f}};

  // V granule layout (verified v3): G = (key>>2)*4 + (d>>4), elem (key&3)*16+(d&15).
  // Staging (PRE=1): LDS 16B-chunk i holds V[key=(i>>5)*4+((i>>1)&3)]
  // [d = ((i>>3)&3)*16 + (i&1)*8 ..+8) -> per-lane pre-swizzled global source,
  // linear LDS dest (global_load_lds writes base + lane*16).
  const int i0 = w * 64 + lane;        // chunk, instr 0
  const int i1 = 256 + w * 64 + lane;  // chunk, instr 1
  const int so0 = (i0 >> 5) * 256 + ((i0 >> 1) & 3) * 64 + ((i0 >> 3) & 3) * 16 + (i0 & 1) * 8;
  const int so1 = (i1 >> 5) * 256 + ((i1 >> 1) & 3) * 64 + ((i1 >> 3) & 3) * 16 + (i1 & 1) * 8;
  const unsigned short* pvh = reinterpret_cast<const unsigned short*>(Vx) + qkvbase;

  // PRE=0 fallback staging (reg round-trip + ds_write)
  const int trow = tid >> 2;
  const int d0c = (tid & 3) << 4;
  const int vwoff = ((trow >> 2) * 4 + (tid & 3)) * 64 + (trow & 3) * 16;
  const float* pvf = reinterpret_cast<const float*>(Vx) + qkvbase + (size_t)trow * D + d0c;

  auto stage = [&](int buf, int t) {
    if constexpr (PRE) {
      const unsigned short* src = pvh + (size_t)t * (64 * D);
      gload_lds16(src + so0, &Vt[buf][w * 512]);
      gload_lds16(src + so1, &Vt[buf][2048 + w * 512]);
    } else {
      const float* p = pvf + (size_t)t * 64 * D;
      float4 a0 = reinterpret_cast<const float4*>(p)[0];
      float4 a1 = reinterpret_cast<const float4*>(p)[1];
      float4 a2 = reinterpret_cast<const float4*>(p)[2];
      float4 a3 = reinterpret_cast<const float4*>(p)[3];
      *reinterpret_cast<short8*>(&Vt[buf][vwoff]) = cvt8(a0, a1);
      *reinterpret_cast<short8*>(&Vt[buf][vwoff + 8]) = cvt8(a2, a3);
    }
  };

  stage(0, 0);
  __syncthreads();  // drains vmcnt -> buf0 resident

  const unsigned int vb0 =
      (unsigned int)(unsigned long long)(const void*)&Vt[0][0] +
      (unsigned int)(quad * 512 + ln15 * 8);

  for (int t = 0; t < 32; ++t) {
    const int cur = t & 1;
    if (t < 31) stage(cur ^ 1, t + 1);  // DMA into other buffer, hides under compute
    unsigned long long mw = mrow[t];
    const int k0 = t * 64;
    short8 bk[4][2];
#pragma unroll
    for (int kt = 0; kt < 4; ++kt) loadK(t * 64 + kt * 16, bk[kt][0], bk[kt][1]);
    unsigned int apu[8];
#pragma unroll
    for (int kt = 0; kt < 4; ++kt) {
      f32x4 acc = {0.f, 0.f, 0.f, 0.f};
      acc = __builtin_amdgcn_mfma_f32_16x16x32_bf16(bk[kt][0], aq0, acc, 0, 0, 0);
      acc = __builtin_amdgcn_mfma_f32_16x16x32_bf16(bk[kt][1], aq1, acc, 0, 0, 0);
      unsigned int nib = (unsigned int)(mw >> (kt * 16 + quad * 4)) & 0xFu;
      f32x4 p;
#pragma unroll
      for (int r = 0; r < 4; ++r) {
        float e = exp2fast(acc[r]) * rinv;
        p[r] = ((nib >> r) & 1u) ? e : 0.f;
      }
      *reinterpret_cast<f32x4*>(arow + k0 + kt * 16 + quad * 4) = p;  // via L2
      // lane owns P[query ln15][key kt*16 + quad*4 + r]; identical key permute on B
      apu[kt * 2] = packbf2(p[0], p[1]);
      apu[kt * 2 + 1] = packbf2(p[2], p[3]);
    }
    // B-frags via tr-reads (v3-verified); granule (m*8+h*4+quad)*4+c, col ln15
    const unsigned int vb = vb0 + (unsigned int)(cur << 13);
    u32x2 x0, x1, x2, x3, x4, x5, x6, x7, x8, x9, x10, x11, x12, x13, x14, x15;
    TRRD(x0, vb, 0);     TRRD(x1, vb, 2048);
    TRRD(x2, vb, 128);   TRRD(x3, vb, 2176);
    TRRD(x4, vb, 256);   TRRD(x5, vb, 2304);
    TRRD(x6, vb, 384);   TRRD(x7, vb, 2432);
    TRRD(x8, vb, 4096);  TRRD(x9, vb, 6144);
    TRRD(x10, vb, 4224); TRRD(x11, vb, 6272);
    TRRD(x12, vb, 4352); TRRD(x13, vb, 6400);
    TRRD(x14, vb, 4480); TRRD(x15, vb, 6528);
    asm volatile("s_waitcnt lgkmcnt(0)" ::: "memory");
    __builtin_amdgcn_sched_barrier(0);  // rule-18: keep MFMAs below the wait
    union Frag { unsigned int u[4]; u32x2 d[2]; short8 s; };
    Frag ap0, ap1, bv;
    ap0.u[0] = apu[0]; ap0.u[1] = apu[1]; ap0.u[2] = apu[2]; ap0.u[3] = apu[3];
    ap1.u[0] = apu[4]; ap1.u[1] = apu[5]; ap1.u[2] = apu[6]; ap1.u[3] = apu[7];
    __builtin_amdgcn_s_setprio(1);
    bv.d[0] = x0;  bv.d[1] = x1;
    oacc[0] = __builtin_amdgcn_mfma_f32_16x16x32_bf16(ap0.s, bv.s, oacc[0], 0, 0, 0);
    bv.d[0] = x2;  bv.d[1] = x3;
    oacc[1] = __builtin_amdgcn_mfma_f32_16x16x32_bf16(ap0.s, bv.s, oacc[1], 0, 0, 0);
    bv.d[0] = x4;  bv.d[1] = x5;
    oacc[2] = __builtin_amdgcn_mfma_f32_16x16x32_bf16(ap0.s, bv.s, oacc[2], 0, 0, 0);
    bv.d[0] = x6;  bv.d[1] = x7;
    oacc[3] = __builtin_amdgcn_mfma_f32_16x16x32_bf16(ap0.s, bv.s, oacc[3], 0, 0, 0);
    bv.d[0] = x8;  bv.d[1] = x9;
    oacc[0] = __builtin_amdgcn_mfma_f32_16x16x32_bf16(ap1.s, bv.s, oacc[0], 0, 0, 0);
    bv.d[0] = x10; bv.d[1] = x11;
    oacc[1] = __builtin_amdgcn_mfma_f32_16x16x32_bf16(ap1.s, bv.s, oacc[1], 0, 0, 0);
    bv.d[0] = x12; bv.d[1] = x13;
    oacc[2] = __builtin_amdgcn_mfma_f32_16x16x32_bf16(ap1.s, bv.s, oacc[2], 0, 0, 0);
    bv.d[0] = x14; bv.d[1] = x15;
    oacc[3] = __builtin_amdgcn_mfma_f32_16x16x32_bf16(ap1.s, bv.s, oacc[3], 0, 0, 0);
    __builtin_amdgcn_s_setprio(0);
    __syncthreads();  // drains DMA for t+1; all waves done reading buf cur
  }

  // epilogue: O store (C rows = query offset quad*4+r, cols = d = c*16+ln15)
#pragma unroll
  for (int c = 0; c < 4; ++c) {
#pragma unroll
    for (int r = 0; r < 4; ++r) {
      Og[qkvbase + (size_t)(q0 + w * 16 + quad * 4 + r) * D + c * 16 + ln15] = oacc[c][r];
    }
  }
}

extern "C" void kernel_launch(void* const* d_in, const int* in_sizes, int n_in,
                              void* d_out, int out_size, void* d_ws, size_t ws_size,
                              hipStream_t stream) {
  const float* q = (const float*)d_in[0];
  const float* k = (const float*)d_in[1];
  const float* v = (const float*)d_in[2];
  const int* m = (const int*)d_in[3];
  float* outp = (float*)d_out;
  float* attnp = outp + (size_t)BB * HH * S * D;

  const size_t bitsBytes = (size_t)BB * S * (S / 64) * 8;  // 1 MB
  unsigned long long* bits = (unsigned long long*)d_ws;
  unsigned short* Kb = (unsigned short*)((char*)d_ws + bitsBytes);
  unsigned short* Vb = Kb + (size_t)NE;
  const bool pre = ws_size >= bitsBytes + 2 * (size_t)NE * sizeof(unsigned short);

  const int nwords = BB * S * (S / 64);  // 131072
  pack_mask_kernel<<<nwords / 4, 256, 0, stream>>>(m, bits);
  dim3 grid(BB * HH, S / 64);
  if (pre) {
    cvt_kv_kernel<<<(2 * (size_t)NE / 8) / 256, 256, 0, stream>>>(k, v, Kb, Vb);
    attn_kernel<1><<<grid, 256, 0, stream>>>(q, Kb, Vb, bits, outp, attnp);
  } else {
    attn_kernel<0><<<grid, 256, 0, stream>>>(q, k, v, bits, outp, attnp);
  }
}